// Round 12
// baseline (379.582 us; speedup 1.0000x reference)
//
#include <hip/hip_runtime.h>

#define C_   128
#define P_   4096
#define K3   384
#define CP   (C_*P_)
#define NB_  32

typedef __attribute__((ext_vector_type(8))) short short8;
typedef __attribute__((ext_vector_type(4))) short short4v;
typedef __attribute__((ext_vector_type(4))) float f32x4;

__device__ __forceinline__ short f2bf(float f) {
  union { float f; unsigned u; } v; v.f = f;
  unsigned r = v.u + 0x7fffu + ((v.u >> 16) & 1u);
  return (short)(r >> 16);
}
__device__ __forceinline__ float bf2f(short b) {
  union { unsigned u; float f; } v; v.u = ((unsigned)(unsigned short)b) << 16;
  return v.f;
}
__device__ __forceinline__ void gl_lds16(const void* g, void* l) {
  __builtin_amdgcn_global_load_lds(
      (const __attribute__((address_space(1))) unsigned int*)g,
      (__attribute__((address_space(3))) unsigned int*)l, 16, 0, 0);
}
// swizzled Bs offset (shorts): element (q,pc) -> conflict-free for BOTH the
// writeB lane pattern (q=lane&3, pc=lane>>2) and the fragment-read pattern
// (q=lane>>4, pc=wp+ip*16+(lane&15)). Round-11 lesson: the old [q][pc] layout
// put write-lanes 0-3 on banks 0-3 (4-way serialize, 4.7M conflict-cycles).
__device__ __forceinline__ int bofs(int q, int pc) {
  return pc * 32 + ((q ^ (pc & 3) ^ ((pc >> 2) & 3)) << 3);
}

// ---- prep: permuted bf16 weights  wXp[m][j*128+c] = wX[m][c*3+j] ----
__global__ __launch_bounds__(256) void prep_kernel(const float* __restrict__ w3,
                                                   const float* __restrict__ w6,
                                                   short* __restrict__ w3p,
                                                   short* __restrict__ w6p) {
  int idx = blockIdx.x * 256 + threadIdx.x;      // 49152 = 128*384
  int m = idx / K3, kp = idx - m * K3;
  int j = kp >> 7, c = kp & 127;
  w3p[idx] = f2bf(w3[m * K3 + c * 3 + j]);
  w6p[idx] = f2bf(w6[m * K3 + c * 3 + j]);
}

// ---- xk: x fp32 -> xb (bf16 natural [c][p]) + xT (bf16 [p][c]) ----
__global__ __launch_bounds__(256) void xk_kernel(const float* __restrict__ x,
                                                 short* __restrict__ xb,
                                                 short* __restrict__ xT) {
  int b = blockIdx.x;                 // 32n * 2ct * 64pt = 4096
  int pt = b & 63, ct = (b >> 6) & 1, n = b >> 7;
  int p0 = pt * 64, c0 = ct * 64;
  const float* xn = x + (size_t)n * CP;
  short* xbn = xb + (size_t)n * CP;
  short* xTn = xT + (size_t)n * CP;
  __shared__ short Ls[64][68];
  int tid = threadIdx.x;
#pragma unroll
  for (int it = 0; it < 4; ++it) {
    int fid = tid + it * 256;
    int i = fid >> 4, j4 = fid & 15;
    f32x4 v = *(const f32x4*)(xn + (c0 + i) * P_ + p0 + j4 * 4);
    short4v s;
#pragma unroll
    for (int r = 0; r < 4; ++r) s[r] = f2bf(v[r]);
    *(short4v*)(xbn + (c0 + i) * P_ + p0 + j4 * 4) = s;
    *(short4v*)(&Ls[i][j4 * 4]) = s;
  }
  __syncthreads();
#pragma unroll
  for (int it = 0; it < 4; ++it) {
    int oid = tid + it * 256;
    int pr = oid >> 4, cg = oid & 15, cb = cg * 4;
    short4v a;
#pragma unroll
    for (int r = 0; r < 4; ++r) a[r] = Ls[cb + r][pr];
    *(short4v*)(xTn + (p0 + pr) * C_ + c0 + cb) = a;
  }
}

// ---- g12: role1: t3T = w3 @ t1 ; role0: t6T/t7T from w6 @ t5(on-the-fly) ----
// XCD-chunked swizzle (round-11: FETCH 133->35 MB) + swizzled Bs (this round).
__global__ __launch_bounds__(256, 4) void g12_kernel(const short* __restrict__ w3p,
                                                     const short* __restrict__ w6p,
                                                     const float* __restrict__ p5,
                                                     const short* __restrict__ xT,
                                                     short* __restrict__ t3T,
                                                     short* __restrict__ t6T,
                                                     short* __restrict__ t7T) {
  int bid = blockIdx.x;                        // nwg = 2048 (%8==0: bijective)
  int blk = (bid & 7) * 256 + (bid >> 3);
  int role = blk & 1;                 // 1: g1 (t3), 0: g2 (t6/t7)
  int b = blk >> 1;
  int n = b >> 5, pt = b & 31, p0 = pt * 128;
  int tid = threadIdx.x, lane = tid & 63, wv = tid >> 6;
  int wm = (wv & 1) * 64, wp = (wv >> 1) * 64;
  const short* Ap = role ? w3p : w6p;
  const short* xTn = xT + (size_t)n * CP;
  __shared__ __align__(16) short As[2][4][128][8];
  __shared__ __align__(16) short Bs[2][4096];   // swizzled (q,pc) via bofs()
  f32x4 acc[4][4] = {};
  short8 bm[2], bl[2], br[2];
  float bp5[2];

  auto stageA = [&](int ks, int bf) {
    int k0 = (ks % 3) * 128 + (ks / 3) * 32;   // k' = jr*128 + cb*32
#pragma unroll
    for (int it = 0; it < 2; ++it) {
      int slot = tid + it * 256;
      int q = slot >> 7, m = slot & 127;
      gl_lds16(Ap + m * K3 + k0 + q * 8, &As[bf][q][m][0]);
    }
  };
  auto loadB = [&](int ks) {
    int jr = ks % 3;
#pragma unroll
    for (int it = 0; it < 2; ++it) {
      int slot = tid + it * 256;
      int q = slot & 3, pc = slot >> 2;      // 4 lanes -> one 64B line
      int p = p0 + pc;
      int c0k = (ks / 3) * 32 + q * 8;
      if (role) {
        int d = 2 * (jr - 1);
        int prc = min(max(p + d, 0), P_ - 1);
        bm[it] = *(const short8*)(xTn + (size_t)prc * C_ + c0k);
      } else {
        int pr = p + 192 * (jr - 1);
        int prc = min(max(pr, 0), P_ - 1);
        int w2 = prc & 63;
        const short* rb = xTn + (size_t)prc * C_ + c0k;
        short8 zero = {};
        bm[it] = *(const short8*)rb;
        bl[it] = (w2 >= 2) ? *(const short8*)(rb - 2 * C_) : zero;
        br[it] = (w2 < 62) ? *(const short8*)(rb + 2 * C_) : zero;
        bp5[it] = p5[prc];
      }
    }
  };
  auto writeB = [&](int ks, int bf) {
    int jr = ks % 3;
#pragma unroll
    for (int it = 0; it < 2; ++it) {
      int slot = tid + it * 256;
      int q = slot & 3, pc = slot >> 2;
      int p = p0 + pc;
      short8 zero = {};
      short8 v;
      if (role) {
        int d = 2 * (jr - 1);
        int wd = (p & 63) + d;
        v = bm[it];
        if (!(wd >= 0 && wd < 64)) v = zero;
      } else {
        int pr = p + 192 * (jr - 1);
        bool rv = (pr >= 0 && pr < P_);
#pragma unroll
        for (int jj = 0; jj < 8; ++jj)
          v[jj] = f2bf(bp5[it] * fmaxf(fmaxf(bf2f(bl[it][jj]), bf2f(bm[it][jj])), bf2f(br[it][jj])));
        if (!rv) v = zero;
      }
      *(short8*)(&Bs[bf][bofs(q, pc)]) = v;
    }
  };

  stageA(0, 0);
  loadB(0);
  writeB(0, 0);
  __syncthreads();
#pragma unroll 2
  for (int ks = 0; ks < 12; ++ks) {
    int cur = ks & 1, nxt = cur ^ 1;
    if (ks < 11) { stageA(ks + 1, nxt); loadB(ks + 1); }   // in flight during MFMA
    int row = lane & 15, q = lane >> 4;
    short8 a[4], bb[4];
#pragma unroll
    for (int im = 0; im < 4; ++im) a[im] = *(const short8*)(&As[cur][q][wm + im * 16 + row][0]);
#pragma unroll
    for (int ip = 0; ip < 4; ++ip) bb[ip] = *(const short8*)(&Bs[cur][bofs(q, wp + ip * 16 + row)]);
#pragma unroll
    for (int im = 0; im < 4; ++im)
#pragma unroll
      for (int ip = 0; ip < 4; ++ip)
        acc[im][ip] = __builtin_amdgcn_mfma_f32_16x16x32_bf16(a[im], bb[ip], acc[im][ip], 0, 0, 0);
    if (ks < 11) writeB(ks + 1, nxt);                      // consume loads after cover
    __syncthreads();
  }
  int col = lane & 15, rq = lane >> 4;
  if (role) {
    short* t3Tn = t3T + (size_t)n * CP;
#pragma unroll
    for (int im = 0; im < 4; ++im)
#pragma unroll
      for (int ip = 0; ip < 4; ++ip) {
        int m0 = wm + im * 16 + rq * 4;
        int p = p0 + wp + ip * 16 + col;
        short4v s;
#pragma unroll
        for (int r = 0; r < 4; ++r) s[r] = f2bf(acc[im][ip][r]);
        *(short4v*)(t3Tn + (size_t)p * C_ + m0) = s;
      }
  } else {
    short* t6Tn = t6T + (size_t)n * CP;
    short* t7Tn = t7T + (size_t)n * CP;
#pragma unroll
    for (int im = 0; im < 4; ++im)
#pragma unroll
      for (int ip = 0; ip < 4; ++ip) {
        int m0 = wm + im * 16 + rq * 4;
        int p = p0 + wp + ip * 16 + col;
        short4v ax = *(const short4v*)(xTn + (size_t)p * C_ + m0);
        short4v s6, s7;
#pragma unroll
        for (int r = 0; r < 4; ++r) {
          float t6v = acc[im][ip][r];
          float t7v = fmaxf(bf2f(ax[r]), t6v);
          s6[r] = f2bf(t6v);
          s7[r] = f2bf(t7v);
        }
        *(short4v*)(t6Tn + (size_t)p * C_ + m0) = s6;
        *(short4v*)(t7Tn + (size_t)p * C_ + m0) = s7;
      }
  }
}

// ---- g3: t9T[k'=(j,cB)][c] += sum_p t1[k',p] * t7T[p][c]   (split-K=8) ----
// XCD swizzle: the 3 nb-blocks per (n,sk) read IDENTICAL t7T B-rows.
// writeAB is lane-linear in LDS (conflict-free) — no swizzle needed.
__global__ __launch_bounds__(256, 4) void g3_kernel(const short* __restrict__ xb,
                                                    const short* __restrict__ t7T,
                                                    float* __restrict__ t9) {
  int bid = blockIdx.x;                        // nwg = 768 (%8==0: bijective)
  int blk = (bid & 7) * 96 + (bid >> 3);
  int nb = blk % 3;
  int tmp = blk / 3;
  int n = tmp & 31, sk = tmp >> 5;
  int d = 2 * (nb - 1);                 // uniform shift for all A rows
  int tid = threadIdx.x, lane = tid & 63, wv = tid >> 6;
  int wm = (wv & 1) * 64, wp = (wv >> 1) * 64;
  const short* xbn = xb + (size_t)n * CP;
  const short* t7n = t7T + (size_t)n * CP;
  __shared__ __align__(16) short As[2][4][128][8];
  __shared__ __align__(16) short Bs[2][4][128][8];
  f32x4 acc[4][4] = {};
  short8 av[2], bv[2];

  auto loadAB = [&](int ks) {
    int pp0 = sk * 512 + ks * 32;
#pragma unroll
    for (int it = 0; it < 2; ++it) {
      int slot = tid + it * 256;
      int q = slot >> 7, rr = slot & 127;
      int pb = pp0 + q * 8;
      // A rows: t1[nb*128+rr][p] = xb[rr][p+d]  (4B-aligned)
      const int* src = (const int*)(xbn + rr * P_ + pb + d);
      union { int i[4]; short8 s; } u;
#pragma unroll
      for (int t = 0; t < 4; ++t) u.i[t] = src[t];
      av[it] = u.s;
      // B: t7T[p][c] gather along p (coalesced across lanes in c)
      const short* bp = t7n + (size_t)pb * C_ + rr;
      short8 w;
#pragma unroll
      for (int j = 0; j < 8; ++j) w[j] = bp[j * C_];
      bv[it] = w;
    }
  };
  auto writeAB = [&](int ks, int bf) {
    int pp0 = sk * 512 + ks * 32;
#pragma unroll
    for (int it = 0; it < 2; ++it) {
      int slot = tid + it * 256;
      int q = slot >> 7, rr = slot & 127;
      int pb = pp0 + q * 8;
      short8 v = av[it];
      int w0 = pb & 63;
      if (nb == 0) { if (w0 == 0) { v[0] = 0; v[1] = 0; } }
      else if (nb == 2) { if (w0 == 56) { v[6] = 0; v[7] = 0; } }
      *(short8*)(&As[bf][q][rr][0]) = v;
      *(short8*)(&Bs[bf][q][rr][0]) = bv[it];
    }
  };

  loadAB(0);
  writeAB(0, 0);
  __syncthreads();
#pragma unroll 2
  for (int ks = 0; ks < 16; ++ks) {
    int cur = ks & 1, nxt = cur ^ 1;
    if (ks < 15) loadAB(ks + 1);
    int row = lane & 15, q = lane >> 4;
    short8 a[4], bb[4];
#pragma unroll
    for (int im = 0; im < 4; ++im) a[im] = *(const short8*)(&As[cur][q][wm + im * 16 + row][0]);
#pragma unroll
    for (int ip = 0; ip < 4; ++ip) bb[ip] = *(const short8*)(&Bs[cur][q][wp + ip * 16 + row][0]);
#pragma unroll
    for (int im = 0; im < 4; ++im)
#pragma unroll
      for (int ip = 0; ip < 4; ++ip)
        acc[im][ip] = __builtin_amdgcn_mfma_f32_16x16x32_bf16(a[im], bb[ip], acc[im][ip], 0, 0, 0);
    if (ks < 15) writeAB(ks + 1, nxt);
    __syncthreads();
  }
  int col = lane & 15, rq = lane >> 4;
  float* t9n = t9 + (size_t)n * (K3 * C_);
#pragma unroll
  for (int im = 0; im < 4; ++im)
#pragma unroll
    for (int ip = 0; ip < 4; ++ip)
#pragma unroll
      for (int r = 0; r < 4; ++r) {
        int kp = nb * 128 + wm + im * 16 + rq * 4 + r;
        int c = wp + ip * 16 + col;
        atomicAdd(&t9n[(size_t)kp * C_ + c], acc[im][ip][r]);   // lane-contiguous
      }
}

// ---- t9s: t9b[n][c][k'] = bf16( t9[n][k'][c] * p8[c] / (64*sqrt(384)) ) ----
__global__ __launch_bounds__(256) void t9s_kernel(const float* __restrict__ t9,
                                                  const float* __restrict__ p8,
                                                  short* __restrict__ t9b) {
  int b = blockIdx.x;                 // 192 = 32n * 6kt
  int n = b / 6, kt = b - n * 6;
  int k0 = kt * 64;
  const float INV = 1.0f / (64.0f * 19.5959179423f);
  const float* t9n = t9 + (size_t)n * (K3 * C_);
  short* t9bn = t9b + (size_t)n * (C_ * K3);
  __shared__ float L[64][132];
  int tid = threadIdx.x;
#pragma unroll
  for (int it = 0; it < 8; ++it) {
    int s = tid + it * 256;           // 2048 f32x4 slots: k = s>>5, c4 = s&31
    int k = s >> 5, c4 = s & 31;
    f32x4 v = *(const f32x4*)(t9n + (size_t)(k0 + k) * C_ + c4 * 4);
    *(f32x4*)(&L[k][c4 * 4]) = v;
  }
  __syncthreads();
#pragma unroll
  for (int it = 0; it < 2; ++it) {
    int s = tid + it * 256;           // 512 slots: c = s>>2, kg = s&3
    int c = s >> 2, kg = s & 3;
    float sc = p8[c] * INV;
    short8 o0, o1;
#pragma unroll
    for (int j = 0; j < 8; ++j) o0[j] = f2bf(L[kg * 16 + j][c] * sc);
#pragma unroll
    for (int j = 0; j < 8; ++j) o1[j] = f2bf(L[kg * 16 + 8 + j][c] * sc);
    short* op = t9bn + (size_t)c * K3 + k0 + kg * 16;
    *(short8*)(op) = o0;
    *(short8*)(op + 8) = o1;
  }
}

// ---- t12k: IN-PLACE materialize t12 slices.
__global__ __launch_bounds__(256) void t12k_kernel(const float* __restrict__ p12,
                                                   const short* __restrict__ xT,
                                                   short* __restrict__ t3T,
                                                   short* __restrict__ t6T,
                                                   short* __restrict__ t7T) {
  int idx = blockIdx.x * 256 + threadIdx.x;   // 8192*256 = 32n*4096p*16cg
  int cg = idx & 15;
  int p  = (idx >> 4) & 4095;
  int n  = idx >> 16;
  size_t base = (size_t)n * CP + (size_t)p * C_ + cg * 8;
  short8 a3 = *(const short8*)(t3T + base);
  short8 a6 = *(const short8*)(t6T + base);
  short8 a7 = *(const short8*)(t7T + base);
  const short* xn = xT + (size_t)n * CP;
  int c0 = cg * 8;
  int h = p >> 6, w = p & 63;
  short8 outv[3];
#pragma unroll
  for (int j = 0; j < 3; ++j) {
    int d = 2 * (j - 1);
    int wd = w + d;
    bool valid = (wd >= 0 && wd < 64);
    int pr = min(max(p + d, 0), P_ - 1);
    short8 ax = *(const short8*)(xn + (size_t)pr * C_ + c0);
    short8 zero = {};
    if (!valid) ax = zero;
    float s12 = p12[j * 64 + h];
    short8 v;
#pragma unroll
    for (int jj = 0; jj < 8; ++jj) {
      float t11 = fmaxf(bf2f(a6[jj]), bf2f(a7[jj]) + fmaxf(bf2f(a3[jj]), bf2f(ax[jj])));
      v[jj] = f2bf(s12 * t11);
    }
    outv[j] = v;
  }
  *(short8*)(t3T + base) = outv[0];
  *(short8*)(t6T + base) = outv[1];
  *(short8*)(t7T + base) = outv[2];
}

// ---- g4: out[c][p] = sum_k' t9b[c][k'] * t12[k'][p] ----
// XCD swizzle + swizzled Bs (same writeB lane pattern as g12).
__global__ __launch_bounds__(256, 4) void g4_kernel(const short* __restrict__ t9b,
                                                    const short* __restrict__ t12,
                                                    float* __restrict__ out) {
  int bid = blockIdx.x;                        // nwg = 1024 (%8==0: bijective)
  int b = (bid & 7) * 128 + (bid >> 3);
  int n = b >> 5, pt = b & 31, p0 = pt * 128;
  int tid = threadIdx.x, lane = tid & 63, wv = tid >> 6;
  int wm = (wv & 1) * 64, wp = (wv >> 1) * 64;
  const short* t9n = t9b + (size_t)n * (K3 * C_);   // [c][k'] pre-scaled bf16
  const size_t SL = (size_t)NB_ * CP;               // slice stride (j)
  __shared__ __align__(16) short As[2][4][128][8];
  __shared__ __align__(16) short Bs[2][4096];       // swizzled via bofs()
  f32x4 acc[4][4] = {};
  short8 bv[2];

  auto stageA = [&](int ks, int bf) {
    int k0 = (ks % 3) * 128 + (ks / 3) * 32;   // k' = j*128 + cb*32
#pragma unroll
    for (int it = 0; it < 2; ++it) {
      int slot = tid + it * 256;
      int q = slot >> 7, m = slot & 127;
      gl_lds16(t9n + (size_t)m * K3 + k0 + q * 8, &As[bf][q][m][0]);
    }
  };
  auto loadB = [&](int ks) {
    int j = ks % 3, cb = ks / 3;
    const short* src = t12 + (size_t)j * SL + (size_t)n * CP;
#pragma unroll
    for (int it = 0; it < 2; ++it) {
      int slot = tid + it * 256;
      int q = slot & 3, pc = slot >> 2;        // 4 lanes -> one 64B line
      bv[it] = *(const short8*)(src + (size_t)(p0 + pc) * C_ + cb * 32 + q * 8);
    }
  };
  auto writeB = [&](int ks, int bf) {
#pragma unroll
    for (int it = 0; it < 2; ++it) {
      int slot = tid + it * 256;
      int q = slot & 3, pc = slot >> 2;
      *(short8*)(&Bs[bf][bofs(q, pc)]) = bv[it];
    }
  };

  stageA(0, 0);
  loadB(0);
  writeB(0, 0);
  __syncthreads();
#pragma unroll 2
  for (int ks = 0; ks < 12; ++ks) {
    int cur = ks & 1, nxt = cur ^ 1;
    if (ks < 11) { stageA(ks + 1, nxt); loadB(ks + 1); }
    int row = lane & 15, q = lane >> 4;
    short8 a[4], bb[4];
#pragma unroll
    for (int im = 0; im < 4; ++im) a[im] = *(const short8*)(&As[cur][q][wm + im * 16 + row][0]);
#pragma unroll
    for (int ip = 0; ip < 4; ++ip) bb[ip] = *(const short8*)(&Bs[cur][bofs(q, wp + ip * 16 + row)]);
#pragma unroll
    for (int im = 0; im < 4; ++im)
#pragma unroll
      for (int ip = 0; ip < 4; ++ip)
        acc[im][ip] = __builtin_amdgcn_mfma_f32_16x16x32_bf16(a[im], bb[ip], acc[im][ip], 0, 0, 0);
    if (ks < 11) writeB(ks + 1, nxt);
    __syncthreads();
  }
  int col = lane & 15, rq = lane >> 4;
#pragma unroll
  for (int im = 0; im < 4; ++im)
#pragma unroll
    for (int ip = 0; ip < 4; ++ip)
#pragma unroll
      for (int r = 0; r < 4; ++r) {
        int m = wm + im * 16 + rq * 4 + r;
        int p = p0 + wp + ip * 16 + col;
        out[(size_t)n * CP + m * P_ + p] = acc[im][ip][r];
      }
}

extern "C" void kernel_launch(void* const* d_in, const int* in_sizes, int n_in,
                              void* d_out, int out_size, void* d_ws, size_t ws_size,
                              hipStream_t stream) {
  const float* x   = (const float*)d_in[0];
  const float* w3  = (const float*)d_in[1];
  const float* p5  = (const float*)d_in[2];
  const float* w6  = (const float*)d_in[3];
  const float* p8  = (const float*)d_in[4];
  const float* p12 = (const float*)d_in[5];
  float* out = (float*)d_out;

  char* ws = (char*)d_ws;
  const size_t RB = (size_t)NB_ * CP * 2;        // 32 MiB per bf16 tensor
  size_t off = 256;                              // guard for small negative-shift reads
  short* xb  = (short*)(ws + off); off += RB;
  short* xT  = (short*)(ws + off); off += RB;
  short* t3T = (short*)(ws + off); off += RB;    // after t12k: t12 slice j=0
  short* t6T = (short*)(ws + off); off += RB;    // after t12k: t12 slice j=1
  short* t7T = (short*)(ws + off); off += RB;    // after t12k: t12 slice j=2
  float* t9  = (float*)(ws + off); off += (size_t)NB_ * K3 * C_ * 4;   // t9 raw [n][384][128]
  short* w3p = (short*)(ws + off); off += 49152 * 2;
  short* w6p = (short*)(ws + off); off += 49152 * 2;
  short* t9b = xb;   // overlay: xb's only consumer (g3) completes before t9s writes

  prep_kernel<<<192, 256, 0, stream>>>(w3, w6, w3p, w6p);
  xk_kernel<<<4096, 256, 0, stream>>>(x, xb, xT);
  g12_kernel<<<2048, 256, 0, stream>>>(w3p, w6p, p5, xT, t3T, t6T, t7T);
  hipMemsetAsync(t9, 0, (size_t)NB_ * K3 * C_ * sizeof(float), stream);
  g3_kernel<<<768, 256, 0, stream>>>(xb, t7T, t9);
  t9s_kernel<<<192, 256, 0, stream>>>(t9, p8, t9b);
  t12k_kernel<<<8192, 256, 0, stream>>>(p12, xT, t3T, t6T, t7T);
  g4_kernel<<<1024, 256, 0, stream>>>(t9b, t3T, out);
}

// Round 13
// 373.279 us; speedup vs baseline: 1.0169x; 1.0169x over previous
//
#include <hip/hip_runtime.h>

#define C_   128
#define P_   4096
#define K3   384
#define CP   (C_*P_)
#define NB_  32
#define PR_  4480   // 192 pad + 4096 + 192 pad (t5p rows per n)

typedef __attribute__((ext_vector_type(8))) short short8;
typedef __attribute__((ext_vector_type(4))) short short4v;
typedef __attribute__((ext_vector_type(4))) float f32x4;

__device__ __forceinline__ short f2bf(float f) {
  union { float f; unsigned u; } v; v.f = f;
  unsigned r = v.u + 0x7fffu + ((v.u >> 16) & 1u);
  return (short)(r >> 16);
}
__device__ __forceinline__ float bf2f(short b) {
  union { unsigned u; float f; } v; v.u = ((unsigned)(unsigned short)b) << 16;
  return v.f;
}
__device__ __forceinline__ void gl_lds16(const void* g, void* l) {
  __builtin_amdgcn_global_load_lds(
      (const __attribute__((address_space(1))) unsigned int*)g,
      (__attribute__((address_space(3))) unsigned int*)l, 16, 0, 0);
}

// ---- prep: permuted bf16 weights  wXp[m][j*128+c] = wX[m][c*3+j] ----
__global__ __launch_bounds__(256) void prep_kernel(const float* __restrict__ w3,
                                                   const float* __restrict__ w6,
                                                   short* __restrict__ w3p,
                                                   short* __restrict__ w6p) {
  int idx = blockIdx.x * 256 + threadIdx.x;      // 49152 = 128*384
  int m = idx / K3, kp = idx - m * K3;
  int j = kp >> 7, c = kp & 127;
  w3p[idx] = f2bf(w3[m * K3 + c * 3 + j]);
  w6p[idx] = f2bf(w6[m * K3 + c * 3 + j]);
}

// ---- xk: x fp32 -> xb (bf16 [c][p]) + xT (bf16 [p][c]) + t5p (padded t5T) ----
// t5 = p5[p] * max3(x[w-2],x[w],x[w+2]) from the LDS tile (taps live inside
// the 64-wide w-row). t5p has 192 zero rows fore/aft per n so g12's shifted
// reads need no bounds logic (round-8 proven content).
__global__ __launch_bounds__(256) void xk_kernel(const float* __restrict__ x,
                                                 const float* __restrict__ p5,
                                                 short* __restrict__ xb,
                                                 short* __restrict__ xT,
                                                 short* __restrict__ t5p) {
  int b = blockIdx.x;                 // 32n * 2ct * 64pt = 4096
  int pt = b & 63, ct = (b >> 6) & 1, n = b >> 7;
  int p0 = pt * 64, c0 = ct * 64;
  const float* xn = x + (size_t)n * CP;
  short* xbn = xb + (size_t)n * CP;
  short* xTn = xT + (size_t)n * CP;
  short* t5n = t5p + (size_t)n * PR_ * C_;
  __shared__ short Ls[64][68];
  int tid = threadIdx.x;
#pragma unroll
  for (int it = 0; it < 4; ++it) {
    int fid = tid + it * 256;
    int i = fid >> 4, j4 = fid & 15;
    f32x4 v = *(const f32x4*)(xn + (c0 + i) * P_ + p0 + j4 * 4);
    short4v s;
#pragma unroll
    for (int r = 0; r < 4; ++r) s[r] = f2bf(v[r]);
    *(short4v*)(xbn + (c0 + i) * P_ + p0 + j4 * 4) = s;
    *(short4v*)(&Ls[i][j4 * 4]) = s;
  }
  __syncthreads();
#pragma unroll
  for (int it = 0; it < 4; ++it) {
    int oid = tid + it * 256;
    int pr = oid >> 4, cg = oid & 15, cb = cg * 4;
    float p5v = p5[p0 + pr];
    short4v a, t5v;
#pragma unroll
    for (int r = 0; r < 4; ++r) {
      a[r] = Ls[cb + r][pr];
      float m = bf2f(a[r]);
      float l = (pr >= 2) ? bf2f(Ls[cb + r][pr - 2]) : 0.0f;
      float rr = (pr < 62) ? bf2f(Ls[cb + r][pr + 2]) : 0.0f;
      t5v[r] = f2bf(p5v * fmaxf(fmaxf(l, m), rr));
    }
    *(short4v*)(xTn + (p0 + pr) * C_ + c0 + cb) = a;
    *(short4v*)(t5n + (size_t)(192 + p0 + pr) * C_ + c0 + cb) = t5v;
  }
}

// ---- g12: role1: t3T = w3 @ t1 ; role0: t6T/t7T = w6 @ t5 (pre-materialized) ----
// XCD-chunked swizzle (round-11: FETCH 133->35 MB). Role0 B = COALESCED
// reg-load of t5p (4 lanes per 64B line, rounds-8+9 lessons combined) +
// ds_write after MFMA; pads replace all bounds logic. Linear Bs (round-12
// bofs reverted: conflicts are hidden in this 2-barrier structure, the
// swizzle address math cost more than it saved).
__global__ __launch_bounds__(256, 4) void g12_kernel(const short* __restrict__ w3p,
                                                     const short* __restrict__ w6p,
                                                     const short* __restrict__ t5p,
                                                     const short* __restrict__ xT,
                                                     short* __restrict__ t3T,
                                                     short* __restrict__ t6T,
                                                     short* __restrict__ t7T) {
  int bid = blockIdx.x;                        // nwg = 2048 (%8==0: bijective)
  int blk = (bid & 7) * 256 + (bid >> 3);
  int role = blk & 1;                 // 1: g1 (t3), 0: g2 (t6/t7)
  int b = blk >> 1;
  int n = b >> 5, pt = b & 31, p0 = pt * 128;
  int tid = threadIdx.x, lane = tid & 63, wv = tid >> 6;
  int wm = (wv & 1) * 64, wp = (wv >> 1) * 64;
  const short* Ap = role ? w3p : w6p;
  const short* xTn = xT + (size_t)n * CP;
  const short* t5n = t5p + (size_t)n * PR_ * C_;
  __shared__ __align__(16) short As[2][4][128][8];
  __shared__ __align__(16) short Bs[2][4][128][8];
  f32x4 acc[4][4] = {};
  short8 bm[2];

  auto stageA = [&](int ks, int bf) {
    int k0 = (ks % 3) * 128 + (ks / 3) * 32;   // k' = jr*128 + cb*32
#pragma unroll
    for (int it = 0; it < 2; ++it) {
      int slot = tid + it * 256;
      int q = slot >> 7, m = slot & 127;
      gl_lds16(Ap + m * K3 + k0 + q * 8, &As[bf][q][m][0]);
    }
  };
  auto loadB = [&](int ks) {
    int jr = ks % 3;
#pragma unroll
    for (int it = 0; it < 2; ++it) {
      int slot = tid + it * 256;
      int q = slot & 3, pc = slot >> 2;      // 4 lanes -> one 64B line
      int p = p0 + pc;
      int c0k = (ks / 3) * 32 + q * 8;
      if (role) {
        int d = 2 * (jr - 1);
        int prc = min(max(p + d, 0), P_ - 1);
        bm[it] = *(const short8*)(xTn + (size_t)prc * C_ + c0k);
      } else {
        int pr = jr * 192 + p;               // padded row: p + 192*(jr-1) + 192
        bm[it] = *(const short8*)(t5n + (size_t)pr * C_ + c0k);
      }
    }
  };
  auto writeB = [&](int ks, int bf) {
    int jr = ks % 3;
#pragma unroll
    for (int it = 0; it < 2; ++it) {
      int slot = tid + it * 256;
      int q = slot & 3, pc = slot >> 2;
      short8 v = bm[it];
      if (role) {
        int d = 2 * (jr - 1);
        int wd = ((p0 + pc) & 63) + d;
        short8 zero = {};
        if (!(wd >= 0 && wd < 64)) v = zero;
      }
      *(short8*)(&Bs[bf][q][pc][0]) = v;
    }
  };

  stageA(0, 0);
  loadB(0);
  writeB(0, 0);
  __syncthreads();
#pragma unroll 2
  for (int ks = 0; ks < 12; ++ks) {
    int cur = ks & 1, nxt = cur ^ 1;
    if (ks < 11) { stageA(ks + 1, nxt); loadB(ks + 1); }   // in flight during MFMA
    int row = lane & 15, q = lane >> 4;
    short8 a[4], bb[4];
#pragma unroll
    for (int im = 0; im < 4; ++im) a[im] = *(const short8*)(&As[cur][q][wm + im * 16 + row][0]);
#pragma unroll
    for (int ip = 0; ip < 4; ++ip) bb[ip] = *(const short8*)(&Bs[cur][q][wp + ip * 16 + row][0]);
#pragma unroll
    for (int im = 0; im < 4; ++im)
#pragma unroll
      for (int ip = 0; ip < 4; ++ip)
        acc[im][ip] = __builtin_amdgcn_mfma_f32_16x16x32_bf16(a[im], bb[ip], acc[im][ip], 0, 0, 0);
    if (ks < 11) writeB(ks + 1, nxt);                      // consume loads after cover
    __syncthreads();
  }
  int col = lane & 15, rq = lane >> 4;
  if (role) {
    short* t3Tn = t3T + (size_t)n * CP;
#pragma unroll
    for (int im = 0; im < 4; ++im)
#pragma unroll
      for (int ip = 0; ip < 4; ++ip) {
        int m0 = wm + im * 16 + rq * 4;
        int p = p0 + wp + ip * 16 + col;
        short4v s;
#pragma unroll
        for (int r = 0; r < 4; ++r) s[r] = f2bf(acc[im][ip][r]);
        *(short4v*)(t3Tn + (size_t)p * C_ + m0) = s;
      }
  } else {
    short* t6Tn = t6T + (size_t)n * CP;
    short* t7Tn = t7T + (size_t)n * CP;
#pragma unroll
    for (int im = 0; im < 4; ++im)
#pragma unroll
      for (int ip = 0; ip < 4; ++ip) {
        int m0 = wm + im * 16 + rq * 4;
        int p = p0 + wp + ip * 16 + col;
        short4v ax = *(const short4v*)(xTn + (size_t)p * C_ + m0);
        short4v s6, s7;
#pragma unroll
        for (int r = 0; r < 4; ++r) {
          float t6v = acc[im][ip][r];
          float t7v = fmaxf(bf2f(ax[r]), t6v);
          s6[r] = f2bf(t6v);
          s7[r] = f2bf(t7v);
        }
        *(short4v*)(t6Tn + (size_t)p * C_ + m0) = s6;
        *(short4v*)(t7Tn + (size_t)p * C_ + m0) = s7;
      }
  }
}

// ---- g3: t9T[k'=(j,cB)][c] += sum_p t1[k',p] * t7T[p][c]   (split-K=8) ----
// XCD swizzle: the 3 nb-blocks per (n,sk) read IDENTICAL t7T B-rows.
__global__ __launch_bounds__(256, 4) void g3_kernel(const short* __restrict__ xb,
                                                    const short* __restrict__ t7T,
                                                    float* __restrict__ t9) {
  int bid = blockIdx.x;                        // nwg = 768 (%8==0: bijective)
  int blk = (bid & 7) * 96 + (bid >> 3);
  int nb = blk % 3;
  int tmp = blk / 3;
  int n = tmp & 31, sk = tmp >> 5;
  int d = 2 * (nb - 1);                 // uniform shift for all A rows
  int tid = threadIdx.x, lane = tid & 63, wv = tid >> 6;
  int wm = (wv & 1) * 64, wp = (wv >> 1) * 64;
  const short* xbn = xb + (size_t)n * CP;
  const short* t7n = t7T + (size_t)n * CP;
  __shared__ __align__(16) short As[2][4][128][8];
  __shared__ __align__(16) short Bs[2][4][128][8];
  f32x4 acc[4][4] = {};
  short8 av[2], bv[2];

  auto loadAB = [&](int ks) {
    int pp0 = sk * 512 + ks * 32;
#pragma unroll
    for (int it = 0; it < 2; ++it) {
      int slot = tid + it * 256;
      int q = slot >> 7, rr = slot & 127;
      int pb = pp0 + q * 8;
      // A rows: t1[nb*128+rr][p] = xb[rr][p+d]  (4B-aligned)
      const int* src = (const int*)(xbn + rr * P_ + pb + d);
      union { int i[4]; short8 s; } u;
#pragma unroll
      for (int t = 0; t < 4; ++t) u.i[t] = src[t];
      av[it] = u.s;
      // B: t7T[p][c] gather along p (coalesced across lanes in c)
      const short* bp = t7n + (size_t)pb * C_ + rr;
      short8 w;
#pragma unroll
      for (int j = 0; j < 8; ++j) w[j] = bp[j * C_];
      bv[it] = w;
    }
  };
  auto writeAB = [&](int ks, int bf) {
    int pp0 = sk * 512 + ks * 32;
#pragma unroll
    for (int it = 0; it < 2; ++it) {
      int slot = tid + it * 256;
      int q = slot >> 7, rr = slot & 127;
      int pb = pp0 + q * 8;
      short8 v = av[it];
      int w0 = pb & 63;
      if (nb == 0) { if (w0 == 0) { v[0] = 0; v[1] = 0; } }
      else if (nb == 2) { if (w0 == 56) { v[6] = 0; v[7] = 0; } }
      *(short8*)(&As[bf][q][rr][0]) = v;
      *(short8*)(&Bs[bf][q][rr][0]) = bv[it];
    }
  };

  loadAB(0);
  writeAB(0, 0);
  __syncthreads();
#pragma unroll 2
  for (int ks = 0; ks < 16; ++ks) {
    int cur = ks & 1, nxt = cur ^ 1;
    if (ks < 15) loadAB(ks + 1);
    int row = lane & 15, q = lane >> 4;
    short8 a[4], bb[4];
#pragma unroll
    for (int im = 0; im < 4; ++im) a[im] = *(const short8*)(&As[cur][q][wm + im * 16 + row][0]);
#pragma unroll
    for (int ip = 0; ip < 4; ++ip) bb[ip] = *(const short8*)(&Bs[cur][q][wp + ip * 16 + row][0]);
#pragma unroll
    for (int im = 0; im < 4; ++im)
#pragma unroll
      for (int ip = 0; ip < 4; ++ip)
        acc[im][ip] = __builtin_amdgcn_mfma_f32_16x16x32_bf16(a[im], bb[ip], acc[im][ip], 0, 0, 0);
    if (ks < 15) writeAB(ks + 1, nxt);
    __syncthreads();
  }
  int col = lane & 15, rq = lane >> 4;
  float* t9n = t9 + (size_t)n * (K3 * C_);
#pragma unroll
  for (int im = 0; im < 4; ++im)
#pragma unroll
    for (int ip = 0; ip < 4; ++ip)
#pragma unroll
      for (int r = 0; r < 4; ++r) {
        int kp = nb * 128 + wm + im * 16 + rq * 4 + r;
        int c = wp + ip * 16 + col;
        atomicAdd(&t9n[(size_t)kp * C_ + c], acc[im][ip][r]);   // lane-contiguous
      }
}

// ---- t9s: t9b[n][c][k'] = bf16( t9[n][k'][c] * p8[c] / (64*sqrt(384)) ) ----
__global__ __launch_bounds__(256) void t9s_kernel(const float* __restrict__ t9,
                                                  const float* __restrict__ p8,
                                                  short* __restrict__ t9b) {
  int b = blockIdx.x;                 // 192 = 32n * 6kt
  int n = b / 6, kt = b - n * 6;
  int k0 = kt * 64;
  const float INV = 1.0f / (64.0f * 19.5959179423f);
  const float* t9n = t9 + (size_t)n * (K3 * C_);
  short* t9bn = t9b + (size_t)n * (C_ * K3);
  __shared__ float L[64][132];
  int tid = threadIdx.x;
#pragma unroll
  for (int it = 0; it < 8; ++it) {
    int s = tid + it * 256;           // 2048 f32x4 slots: k = s>>5, c4 = s&31
    int k = s >> 5, c4 = s & 31;
    f32x4 v = *(const f32x4*)(t9n + (size_t)(k0 + k) * C_ + c4 * 4);
    *(f32x4*)(&L[k][c4 * 4]) = v;
  }
  __syncthreads();
#pragma unroll
  for (int it = 0; it < 2; ++it) {
    int s = tid + it * 256;           // 512 slots: c = s>>2, kg = s&3
    int c = s >> 2, kg = s & 3;
    float sc = p8[c] * INV;
    short8 o0, o1;
#pragma unroll
    for (int j = 0; j < 8; ++j) o0[j] = f2bf(L[kg * 16 + j][c] * sc);
#pragma unroll
    for (int j = 0; j < 8; ++j) o1[j] = f2bf(L[kg * 16 + 8 + j][c] * sc);
    short* op = t9bn + (size_t)c * K3 + k0 + kg * 16;
    *(short8*)(op) = o0;
    *(short8*)(op + 8) = o1;
  }
}

// ---- t12k: IN-PLACE materialize t12 slices.
// t3T <- t12(j=0), t6T <- t12(j=1), t7T <- t12(j=2). Per-thread in-place map;
// only xT is read at p+-2 and xT is never written -> no races.
__global__ __launch_bounds__(256) void t12k_kernel(const float* __restrict__ p12,
                                                   const short* __restrict__ xT,
                                                   short* __restrict__ t3T,
                                                   short* __restrict__ t6T,
                                                   short* __restrict__ t7T) {
  int idx = blockIdx.x * 256 + threadIdx.x;   // 8192*256 = 32n*4096p*16cg
  int cg = idx & 15;
  int p  = (idx >> 4) & 4095;
  int n  = idx >> 16;
  size_t base = (size_t)n * CP + (size_t)p * C_ + cg * 8;
  short8 a3 = *(const short8*)(t3T + base);
  short8 a6 = *(const short8*)(t6T + base);
  short8 a7 = *(const short8*)(t7T + base);
  const short* xn = xT + (size_t)n * CP;
  int c0 = cg * 8;
  int h = p >> 6, w = p & 63;
  short8 outv[3];
#pragma unroll
  for (int j = 0; j < 3; ++j) {
    int d = 2 * (j - 1);
    int wd = w + d;
    bool valid = (wd >= 0 && wd < 64);
    int pr = min(max(p + d, 0), P_ - 1);
    short8 ax = *(const short8*)(xn + (size_t)pr * C_ + c0);
    short8 zero = {};
    if (!valid) ax = zero;
    float s12 = p12[j * 64 + h];
    short8 v;
#pragma unroll
    for (int jj = 0; jj < 8; ++jj) {
      float t11 = fmaxf(bf2f(a6[jj]), bf2f(a7[jj]) + fmaxf(bf2f(a3[jj]), bf2f(ax[jj])));
      v[jj] = f2bf(s12 * t11);
    }
    outv[j] = v;
  }
  *(short8*)(t3T + base) = outv[0];
  *(short8*)(t6T + base) = outv[1];
  *(short8*)(t7T + base) = outv[2];
}

// ---- g4: out[c][p] = sum_k' t9b[c][k'] * t12[k'][p] ----
// XCD swizzle; A via gl_lds; B via coalesced reg-load + ds_write (round-9
// lesson); linear Bs (round-12 revert).
__global__ __launch_bounds__(256, 4) void g4_kernel(const short* __restrict__ t9b,
                                                    const short* __restrict__ t12,
                                                    float* __restrict__ out) {
  int bid = blockIdx.x;                        // nwg = 1024 (%8==0: bijective)
  int b = (bid & 7) * 128 + (bid >> 3);
  int n = b >> 5, pt = b & 31, p0 = pt * 128;
  int tid = threadIdx.x, lane = tid & 63, wv = tid >> 6;
  int wm = (wv & 1) * 64, wp = (wv >> 1) * 64;
  const short* t9n = t9b + (size_t)n * (K3 * C_);   // [c][k'] pre-scaled bf16
  const size_t SL = (size_t)NB_ * CP;               // slice stride (j)
  __shared__ __align__(16) short As[2][4][128][8];
  __shared__ __align__(16) short Bs[2][4][128][8];
  f32x4 acc[4][4] = {};
  short8 bv[2];

  auto stageA = [&](int ks, int bf) {
    int k0 = (ks % 3) * 128 + (ks / 3) * 32;   // k' = j*128 + cb*32
#pragma unroll
    for (int it = 0; it < 2; ++it) {
      int slot = tid + it * 256;
      int q = slot >> 7, m = slot & 127;
      gl_lds16(t9n + (size_t)m * K3 + k0 + q * 8, &As[bf][q][m][0]);
    }
  };
  auto loadB = [&](int ks) {
    int j = ks % 3, cb = ks / 3;
    const short* src = t12 + (size_t)j * SL + (size_t)n * CP;
#pragma unroll
    for (int it = 0; it < 2; ++it) {
      int slot = tid + it * 256;
      int q = slot & 3, pc = slot >> 2;        // 4 lanes -> one 64B line
      bv[it] = *(const short8*)(src + (size_t)(p0 + pc) * C_ + cb * 32 + q * 8);
    }
  };
  auto writeB = [&](int ks, int bf) {
#pragma unroll
    for (int it = 0; it < 2; ++it) {
      int slot = tid + it * 256;
      int q = slot & 3, pc = slot >> 2;
      *(short8*)(&Bs[bf][q][pc][0]) = bv[it];
    }
  };

  stageA(0, 0);
  loadB(0);
  writeB(0, 0);
  __syncthreads();
#pragma unroll 2
  for (int ks = 0; ks < 12; ++ks) {
    int cur = ks & 1, nxt = cur ^ 1;
    if (ks < 11) { stageA(ks + 1, nxt); loadB(ks + 1); }
    int row = lane & 15, q = lane >> 4;
    short8 a[4], bb[4];
#pragma unroll
    for (int im = 0; im < 4; ++im) a[im] = *(const short8*)(&As[cur][q][wm + im * 16 + row][0]);
#pragma unroll
    for (int ip = 0; ip < 4; ++ip) bb[ip] = *(const short8*)(&Bs[cur][q][wp + ip * 16 + row][0]);
#pragma unroll
    for (int im = 0; im < 4; ++im)
#pragma unroll
      for (int ip = 0; ip < 4; ++ip)
        acc[im][ip] = __builtin_amdgcn_mfma_f32_16x16x32_bf16(a[im], bb[ip], acc[im][ip], 0, 0, 0);
    if (ks < 11) writeB(ks + 1, nxt);
    __syncthreads();
  }
  int col = lane & 15, rq = lane >> 4;
#pragma unroll
  for (int im = 0; im < 4; ++im)
#pragma unroll
    for (int ip = 0; ip < 4; ++ip)
#pragma unroll
      for (int r = 0; r < 4; ++r) {
        int m = wm + im * 16 + rq * 4 + r;
        int p = p0 + wp + ip * 16 + col;
        out[(size_t)n * CP + m * P_ + p] = acc[im][ip][r];
      }
}

extern "C" void kernel_launch(void* const* d_in, const int* in_sizes, int n_in,
                              void* d_out, int out_size, void* d_ws, size_t ws_size,
                              hipStream_t stream) {
  const float* x   = (const float*)d_in[0];
  const float* w3  = (const float*)d_in[1];
  const float* p5  = (const float*)d_in[2];
  const float* w6  = (const float*)d_in[3];
  const float* p8  = (const float*)d_in[4];
  const float* p12 = (const float*)d_in[5];
  float* out = (float*)d_out;

  char* ws = (char*)d_ws;
  const size_t RB = (size_t)NB_ * CP * 2;        // 32 MiB per bf16 tensor
  size_t off = 256;                              // guard for small negative-shift reads
  short* xb  = (short*)(ws + off); off += RB;
  short* xT  = (short*)(ws + off); off += RB;
  short* t3T = (short*)(ws + off); off += RB;    // after t12k: t12 slice j=0
  short* t6T = (short*)(ws + off); off += RB;    // after t12k: t12 slice j=1
  short* t7T = (short*)(ws + off); off += RB;    // after t12k: t12 slice j=2
  float* t9  = (float*)(ws + off); off += (size_t)NB_ * K3 * C_ * 4;   // t9 raw [n][384][128]
  short* w3p = (short*)(ws + off); off += 49152 * 2;
  short* w6p = (short*)(ws + off); off += 49152 * 2;
  short* t9b = xb;            // overlay: xb's only consumer (g3) completes first
  short* t5p = (short*)out;   // scratch in d_out (36.7 MB < 64 MB; g4 writes out last)

  prep_kernel<<<192, 256, 0, stream>>>(w3, w6, w3p, w6p);
  hipMemsetAsync(t5p, 0, (size_t)NB_ * PR_ * C_ * 2, stream);   // zero pads
  xk_kernel<<<4096, 256, 0, stream>>>(x, p5, xb, xT, t5p);
  g12_kernel<<<2048, 256, 0, stream>>>(w3p, w6p, t5p, xT, t3T, t6T, t7T);
  hipMemsetAsync(t9, 0, (size_t)NB_ * K3 * C_ * sizeof(float), stream);
  g3_kernel<<<768, 256, 0, stream>>>(xb, t7T, t9);
  t9s_kernel<<<192, 256, 0, stream>>>(t9, p8, t9b);
  t12k_kernel<<<8192, 256, 0, stream>>>(p12, xT, t3T, t6T, t7T);
  g4_kernel<<<1024, 256, 0, stream>>>(t9b, t3T, out);
}